// Round 9
// baseline (358.345 us; speedup 1.0000x reference)
//
#include <hip/hip_runtime.h>
#include <hip/hip_bf16.h>

#define N_NODES 50000
#define N_EDGES 800000
#define D_IN 128
#define D_HID 512
#define D_OUT 128
#define CAT_DIM 640   // D_IN + D_HID
#define CAP 64        // per-node edge-bucket capacity (Poisson(16): P(>=64) ~ 1e-20)

typedef __attribute__((ext_vector_type(8))) short short8;
typedef __attribute__((ext_vector_type(4))) float floatx4;

__device__ __forceinline__ unsigned short f2bf(float f) {
    unsigned u = __float_as_uint(f);
    unsigned r = u + 0x7fffu + ((u >> 16) & 1u);   // RNE
    return (unsigned short)(r >> 16);
}

// ================= prep: cast X -> concat[:,0:128], weight transposes, detect

#define PREP_CASTX_BLOCKS   6250   // 50000*32 threads / 256
#define PREP_FCW_BLOCKS      256   // 128*512 / 256
#define PREP_W2_BLOCKS       320   // 640*128 / 256
#define PREP_TOTAL (PREP_CASTX_BLOCKS + PREP_FCW_BLOCKS + PREP_W2_BLOCKS + 1)

__global__ void prep_kernel(const float* __restrict__ X, const float* __restrict__ fcW,
                            const float* __restrict__ Wm, const int* __restrict__ adj,
                            unsigned short* __restrict__ concat,
                            unsigned short* __restrict__ fcwT,
                            unsigned short* __restrict__ WT,
                            int* __restrict__ flag) {
    int b = blockIdx.x;
    int tid = threadIdx.x;
    if (b < PREP_CASTX_BLOCKS) {
        int t = b * 256 + tid;                 // 50000*32
        int row = t >> 5;
        int cg2 = (t & 31) * 4;
        float4 v = *(const float4*)(X + (size_t)row * D_IN + cg2);
        unsigned short o[4] = { f2bf(v.x), f2bf(v.y), f2bf(v.z), f2bf(v.w) };
        *(unsigned long long*)(concat + (size_t)row * CAT_DIM + cg2) = *(unsigned long long*)o;
        return;
    }
    b -= PREP_CASTX_BLOCKS;
    if (b < PREP_FCW_BLOCKS) {
        int idx = b * 256 + tid;               // 128*512
        int k = idx >> 9;
        int n = idx & (D_HID - 1);
        fcwT[n * D_IN + k] = f2bf(fcW[idx]);
        return;
    }
    b -= PREP_FCW_BLOCKS;
    if (b < PREP_W2_BLOCKS) {
        int idx = b * 256 + tid;               // 640*128
        int k = idx >> 7;
        int n = idx & (D_OUT - 1);
        WT[n * CAT_DIM + k] = f2bf(Wm[idx]);
        return;
    }
    // detect (wave 0): int64 high words all zero (node ids < 2^31)
    if (tid < 64) {
        int v = adj[2 * tid + 1];
        unsigned long long m = __ballot(v != 0);
        if (tid == 0) *flag = (m == 0ULL) ? 2 : 1;   // 2 => int64 stride
    }
}

// ================= hist (device fn) ========================================

__device__ __forceinline__ void hist_edges(const int* __restrict__ adj, int s, int e0,
                                           int* __restrict__ deg, int* __restrict__ edge_list) {
    int src0, src1, trg0, trg1;
    if (s == 2) {   // int64: edges e0,e0+1 -> adj dwords [2e0 .. 2e0+3], coalesced
        int4 vs = *(const int4*)(adj + 2 * (size_t)e0);
        int4 vt = *(const int4*)(adj + 2 * ((size_t)N_EDGES + e0));
        src0 = vs.x; src1 = vs.z;
        trg0 = vt.x; trg1 = vt.z;
    } else {        // int32
        int2 vs = *(const int2*)(adj + e0);
        int2 vt = *(const int2*)(adj + N_EDGES + e0);
        src0 = vs.x; src1 = vs.y;
        trg0 = vt.x; trg1 = vt.y;
    }
    int p0 = atomicAdd(&deg[src0], 1);
    if (p0 < CAP) edge_list[src0 * CAP + p0] = trg0;
    int p1 = atomicAdd(&deg[src1], 1);
    if (p1 < CAP) edge_list[src1 * CAP + p1] = trg1;
}

// ================= barrier-free, LDS-free MFMA tile ========================
// C 64x128 block at rows [bm,bm+64), cols [bn,bn+128). 2x2 waves, 32x64 wave
// tiles. A/B fragments loaded straight from global: a wave frag load = 16
// rows x 64 B = 16 cache lines (same line count as coalesced); B is L2-hot
// (fcwT 128 KB / WT 163 KB). No __syncthreads, no __shared__ -> full
// occupancy for any co-resident latency-bound blocks.
// OUT_MODE: 0 = f32 store, 1 = bf16 store, 2 = f32 read-modify-write add.

template<int BIAS_RELU, int OUT_MODE>
__device__ __forceinline__ void mfma_tile_nolds(
    const unsigned short* __restrict__ A, int lda,
    const unsigned short* __restrict__ Bt, int ldb,
    const float* __restrict__ bias, void* __restrict__ C, int ldc,
    int M, int k_lo, int k_hi, int bm, int bn)
{
    int tid = threadIdx.x;
    int lane = tid & 63, w = tid >> 6;
    int wm = (w >> 1) * 32, wn = (w & 1) * 64;
    int q = lane >> 4, l16 = lane & 15;
    floatx4 acc[2][4] = {};

    int arow0 = bm + wm + l16;
    int arow1 = arow0 + 16;
    bool v0 = arow0 < M, v1 = arow1 < M;
    const unsigned short* a0 = A + (size_t)arow0 * lda + q * 8;
    const unsigned short* a1 = A + (size_t)arow1 * lda + q * 8;
    const unsigned short* bp0 = Bt + (size_t)(bn + wn + l16) * ldb + q * 8;
    const unsigned short* bp1 = bp0 + (size_t)16 * ldb;
    const unsigned short* bp2 = bp0 + (size_t)32 * ldb;
    const unsigned short* bp3 = bp0 + (size_t)48 * ldb;

    #pragma unroll 4
    for (int k0 = k_lo; k0 < k_hi; k0 += 32) {
        short8 af0 = {}, af1 = {};
        if (v0) af0 = *(const short8*)(a0 + k0);
        if (v1) af1 = *(const short8*)(a1 + k0);
        short8 bf[4];
        bf[0] = *(const short8*)(bp0 + k0);
        bf[1] = *(const short8*)(bp1 + k0);
        bf[2] = *(const short8*)(bp2 + k0);
        bf[3] = *(const short8*)(bp3 + k0);
        #pragma unroll
        for (int ni = 0; ni < 4; ++ni) {
            acc[0][ni] = __builtin_amdgcn_mfma_f32_16x16x32_bf16(af0, bf[ni], acc[0][ni], 0, 0, 0);
            acc[1][ni] = __builtin_amdgcn_mfma_f32_16x16x32_bf16(af1, bf[ni], acc[1][ni], 0, 0, 0);
        }
    }

    #pragma unroll
    for (int mi = 0; mi < 2; ++mi) {
        #pragma unroll
        for (int ni = 0; ni < 4; ++ni) {
            #pragma unroll
            for (int r = 0; r < 4; ++r) {
                int row = bm + wm + mi * 16 + q * 4 + r;
                int col = bn + wn + ni * 16 + l16;
                if (row < M) {
                    float v = acc[mi][ni][r];
                    if (BIAS_RELU) v = fmaxf(v + bias[col], 0.0f);
                    if (OUT_MODE == 0)
                        ((float*)C)[(size_t)row * ldc + col] = v;
                    else if (OUT_MODE == 1)
                        ((unsigned short*)C)[(size_t)row * ldc + col] = f2bf(v);
                    else {
                        float* o = (float*)C + (size_t)row * ldc + col;
                        *o = *o + v;
                    }
                }
            }
        }
    }
}

// ================= mid: hist blocks + LDS-free GEMM1 blocks ================

#define HIST_VB   1563   // ceil((N_EDGES/2)/256)
#define GEMM1_MT   782   // ceil(50000/64)
#define GEMM1_TILES (GEMM1_MT * 4)

__global__ __launch_bounds__(256)
void mid_kernel(const int* __restrict__ adj, const int* __restrict__ flag,
                int* __restrict__ deg, int* __restrict__ edge_list,
                const unsigned short* __restrict__ concat,
                const unsigned short* __restrict__ fcwT,
                const float* __restrict__ fcb,
                unsigned short* __restrict__ F) {
    if (blockIdx.x < HIST_VB) {
        int e0 = (blockIdx.x * 256 + threadIdx.x) * 2;
        if (e0 < N_EDGES) hist_edges(adj, flag[0], e0, deg, edge_list);
        return;
    }
    int tile = blockIdx.x - HIST_VB;
    mfma_tile_nolds<1, 1>(concat, CAT_DIM, fcwT, D_IN, fcb, F, D_HID,
                          N_NODES, 0, D_IN, (tile >> 2) * 64, (tile & 3) * 128);
}

// ================= aggmix: gemm2a blocks (X-part of GEMM2) + aggregate =====
// gemm2a (independent of aggregate) runs first in grid order and hides under
// the 114 us gather; zero LDS so aggregate keeps full occupancy.

#define GEMM2A_VB 782

__device__ __forceinline__ void fmax_bf16x8(float* acc, const uint4& p) {
    const unsigned* a = (const unsigned*)&p;
    #pragma unroll
    for (int j = 0; j < 4; ++j) {
        unsigned u = a[j];
        acc[2 * j]     = fmaxf(acc[2 * j],     __uint_as_float(u << 16));
        acc[2 * j + 1] = fmaxf(acc[2 * j + 1], __uint_as_float(u & 0xffff0000u));
    }
}

__global__ __launch_bounds__(256)
void aggmix_kernel(const unsigned short* __restrict__ F,
                   const int* __restrict__ deg,
                   const int* __restrict__ edge_list,
                   unsigned short* __restrict__ concat,
                   const unsigned short* __restrict__ WT,
                   float* __restrict__ out) {
    if (blockIdx.x < GEMM2A_VB) {
        mfma_tile_nolds<0, 0>(concat, CAT_DIM, WT, CAT_DIM, nullptr, out, D_OUT,
                              N_NODES, 0, D_IN, blockIdx.x * 64, 0);
        return;
    }
    // aggregate: wave per node, lane owns 8 of 512 dims (proven 114 us form)
    int gw = (blockIdx.x - GEMM2A_VB) * 4 + (threadIdx.x >> 6);
    if (gw >= N_NODES) return;
    int lane = threadIdx.x & 63;
    int d = deg[gw];
    d = d < CAP ? d : CAP;
    const int* el = edge_list + gw * CAP;
    float acc[8] = {0.f, 0.f, 0.f, 0.f, 0.f, 0.f, 0.f, 0.f};
    int i = 0;
    for (; i + 2 <= d; i += 2) {
        int t0 = el[i], t1 = el[i + 1];
        uint4 p0 = *(const uint4*)(F + (size_t)t0 * D_HID + lane * 8);
        uint4 p1 = *(const uint4*)(F + (size_t)t1 * D_HID + lane * 8);
        fmax_bf16x8(acc, p0);
        fmax_bf16x8(acc, p1);
    }
    if (i < d) {
        uint4 p0 = *(const uint4*)(F + (size_t)el[i] * D_HID + lane * 8);
        fmax_bf16x8(acc, p0);
    }
    unsigned o[4];
    #pragma unroll
    for (int j = 0; j < 4; ++j) {
        unsigned lo = __float_as_uint(acc[2 * j]) >> 16;          // exact: maxima of bf16 values
        unsigned hi = __float_as_uint(acc[2 * j + 1]) & 0xffff0000u;
        o[j] = lo | hi;
    }
    *(uint4*)(concat + (size_t)gw * CAT_DIM + D_IN + lane * 8) = *(uint4*)o;
}

// ================= gemm2b: agg-part of GEMM2, += into out ==================

__global__ __launch_bounds__(256)
void gemm2b_kernel(const unsigned short* __restrict__ concat,
                   const unsigned short* __restrict__ WT,
                   float* __restrict__ out) {
    mfma_tile_nolds<0, 2>(concat, CAT_DIM, WT, CAT_DIM, nullptr, out, D_OUT,
                          N_NODES, D_IN, CAT_DIM, blockIdx.x * 64, 0);
}

// ================= host launch =============================================

extern "C" void kernel_launch(void* const* d_in, const int* in_sizes, int n_in,
                              void* d_out, int out_size, void* d_ws, size_t ws_size,
                              hipStream_t stream) {
    const float* X    = (const float*)d_in[0];
    const float* fc_w = (const float*)d_in[1];
    const float* fc_b = (const float*)d_in[2];
    const float* Wm   = (const float*)d_in[3];
    const int*   adj  = (const int*)d_in[4];
    float* outp = (float*)d_out;

    char* ws = (char*)d_ws;
    size_t off = 0;
    auto alloc = [&](size_t bytes) -> void* {
        void* p = ws + off;
        off = (off + bytes + 255) & ~(size_t)255;
        return p;
    };
    unsigned short* concat = (unsigned short*)alloc((size_t)N_NODES * CAT_DIM * 2);
    unsigned short* F      = (unsigned short*)alloc((size_t)N_NODES * D_HID * 2);
    unsigned short* fcwT   = (unsigned short*)alloc((size_t)D_HID * D_IN * 2);
    unsigned short* WT     = (unsigned short*)alloc((size_t)D_OUT * CAT_DIM * 2);
    int* deg       = (int*)alloc((size_t)N_NODES * 4);
    int* edge_list = (int*)alloc((size_t)N_NODES * CAP * 4);
    int* flag      = (int*)alloc(256);

    hipMemsetAsync(deg, 0, (size_t)N_NODES * 4, stream);
    prep_kernel<<<PREP_TOTAL, 256, 0, stream>>>(X, fc_w, Wm, adj, concat, fcwT, WT, flag);
    mid_kernel<<<HIST_VB + GEMM1_TILES, 256, 0, stream>>>(adj, flag, deg, edge_list,
                                                          concat, fcwT, fc_b, F);
    aggmix_kernel<<<GEMM2A_VB + (N_NODES / 4), 256, 0, stream>>>(F, deg, edge_list,
                                                                 concat, WT, outp);
    gemm2b_kernel<<<GEMM1_MT, 256, 0, stream>>>(concat, WT, outp);
}